// Round 1
// baseline (537.259 us; speedup 1.0000x reference)
//
#include <hip/hip_runtime.h>
#include <cstddef>

#define NB 16384
#define GB 4

// ---- ws float offsets ----
#define OFF_W1T 0                      // 4*3*64   = 768
#define OFF_W2T 768                    // 64*5*64  = 20480
#define OFF_W3T 21248                  // 64*7*64  = 28672
#define OFF_SC1 49920
#define OFF_SH1 49984
#define OFF_SC2 50048
#define OFF_SH2 50112
#define OFF_SC3 50176
#define OFF_SH3 50240
#define OFF_PB  50304                  // 4*16
#define OFF_PBB 50368                  // 16
#define OFF_CO  50384                  // 16*64
#define OFF_SF  51408                  // NB*64
#define OFF_H   (51408 + NB*64)        // NB*16

// ============================ prep ============================
__global__ __launch_bounds__(256) void prep_kernel(
    const float* __restrict__ conv1_w, const float* __restrict__ conv1_b,
    const float* __restrict__ conv2_w, const float* __restrict__ conv2_b,
    const float* __restrict__ conv3_w, const float* __restrict__ conv3_b,
    const float* __restrict__ bn1_g, const float* __restrict__ bn1_b,
    const float* __restrict__ bn2_g, const float* __restrict__ bn2_b,
    const float* __restrict__ bn3_g, const float* __restrict__ bn3_b,
    const float* __restrict__ proj_w, const float* __restrict__ proj_b,
    const float* __restrict__ A, const float* __restrict__ Bm,
    const float* __restrict__ Cm, const float* __restrict__ out_w,
    float* __restrict__ ws)
{
  int tid = blockIdx.x * blockDim.x + threadIdx.x;
  int nt = gridDim.x * blockDim.x;
  const float s = rsqrtf(1.0f + 1e-5f);

  for (int i = tid; i < 64*4*3; i += nt) {      // w1t[(ic*3+k)*64+o]
    int o = i & 63, rk = i >> 6;
    ws[OFF_W1T + i] = conv1_w[o*12 + rk];
  }
  for (int i = tid; i < 64*64*5; i += nt) {     // w2t[(ic*5+k)*64+o]
    int o = i & 63, rk = i >> 6;
    ws[OFF_W2T + i] = conv2_w[o*320 + rk];
  }
  for (int i = tid; i < 64*64*7; i += nt) {     // w3t[(ic*7+k)*64+o]
    int o = i & 63, rk = i >> 6;
    ws[OFF_W3T + i] = conv3_w[o*448 + rk];
  }
  for (int o = tid; o < 64; o += nt) {
    float s1 = bn1_g[o]*s, s2 = bn2_g[o]*s, s3 = bn3_g[o]*s;
    ws[OFF_SC1+o] = s1; ws[OFF_SH1+o] = s1*conv1_b[o] + bn1_b[o];
    ws[OFF_SC2+o] = s2; ws[OFF_SH2+o] = s2*conv2_b[o] + bn2_b[o];
    ws[OFF_SC3+o] = s3; ws[OFF_SH3+o] = s3*conv3_b[o] + bn3_b[o];
  }
  // PB[c][j] = sum_m proj_w[c][m]*Bm[m][j]
  for (int i = tid; i < 64; i += nt) {
    int c = i >> 4, j = i & 15;
    float acc = 0.f;
    for (int m = 0; m < 64; ++m) acc += proj_w[c*64+m]*Bm[m*16+j];
    ws[OFF_PB + i] = acc;
  }
  for (int j = tid; j < 16; j += nt) {
    float acc = 0.f;
    for (int m = 0; m < 64; ++m) acc += proj_b[m]*Bm[m*16+j];
    ws[OFF_PBB + j] = acc;
  }
  // CO[j][o] = sum_m Cm[j][m]*out_w[m][o]
  for (int i = tid; i < 16*64; i += nt) {
    int j = i >> 6, o = i & 63;
    float acc = 0.f;
    for (int m = 0; m < 64; ++m) acc += Cm[j*64+m]*out_w[m*64+o];
    ws[OFF_CO + i] = acc;
  }
}

// ============================ conv stack ============================
// Row layout: arow[i] = act[t = i-3]; valid t 0..9 at i=3..12, zeros at 0..2,13..15.
// conv pad p kernel K: out[t] = sum_k w[k]*act[t+k-p] -> index t+k-p+3.
__global__ __launch_bounds__(128) void conv_kernel(
    const float* __restrict__ x, const float* __restrict__ wsr,
    float* __restrict__ sfp)
{
  __shared__ float act[2][GB][64][16];  // 32 KB
  __shared__ float a0[2][GB][4][16];    // 2 KB
  const int lane = threadIdx.x & 63;
  const int wid = threadIdx.x >> 6;
  const int bg = (blockIdx.x * 2 + wid) * GB;
  float (*myact)[64][16] = act[wid];
  float (*mya0)[4][16] = a0[wid];

  const float* w1t = wsr + OFF_W1T;
  const float* w2t = wsr + OFF_W2T;
  const float* w3t = wsr + OFF_W3T;

  for (int i = lane; i < GB*4*16; i += 64) ((float*)mya0)[i] = 0.f;
  __syncthreads();
  for (int i = lane; i < GB*40; i += 64) {
    int g = i / 40, r = i % 40, t = r >> 2, c = r & 3;
    mya0[g][c][3+t] = x[(size_t)(bg+g)*400 + (90+t)*4 + c];
  }
  __syncthreads();

  float acc[GB][10];

  // ---- conv1: K=3, p=1 -> idx t+k+2 ----
  #pragma unroll
  for (int g = 0; g < GB; ++g)
    #pragma unroll
    for (int t = 0; t < 10; ++t) acc[g][t] = 0.f;
  #pragma unroll
  for (int ic = 0; ic < 4; ++ic) {
    float w0 = w1t[(ic*3+0)*64+lane];
    float w1 = w1t[(ic*3+1)*64+lane];
    float w2 = w1t[(ic*3+2)*64+lane];
    #pragma unroll
    for (int g = 0; g < GB; ++g) {
      float ar[16];
      const float4* rp = (const float4*)mya0[g][ic];
      #pragma unroll
      for (int q = 0; q < 4; ++q) { float4 v = rp[q]; ar[4*q]=v.x; ar[4*q+1]=v.y; ar[4*q+2]=v.z; ar[4*q+3]=v.w; }
      #pragma unroll
      for (int t = 0; t < 10; ++t)
        acc[g][t] += w0*ar[t+2] + w1*ar[t+3] + w2*ar[t+4];
    }
  }
  {
    float sc = wsr[OFF_SC1+lane], sh = wsr[OFF_SH1+lane];
    __syncthreads();
    #pragma unroll
    for (int g = 0; g < GB; ++g) {
      float* row = myact[g][lane];
      row[0]=0.f; row[1]=0.f; row[2]=0.f; row[13]=0.f; row[14]=0.f; row[15]=0.f;
      #pragma unroll
      for (int t = 0; t < 10; ++t) { float v = sc*acc[g][t] + sh; row[3+t] = v > 0.f ? v : 0.f; }
    }
    __syncthreads();
  }

  // ---- conv2: K=5, p=2 -> idx t+k+1 ----
  #pragma unroll
  for (int g = 0; g < GB; ++g)
    #pragma unroll
    for (int t = 0; t < 10; ++t) acc[g][t] = 0.f;
  {
    float w[5], wn[5];
    #pragma unroll
    for (int k = 0; k < 5; ++k) w[k] = w2t[k*64+lane];
    for (int ic = 0; ic < 64; ++ic) {
      if (ic < 63) {
        #pragma unroll
        for (int k = 0; k < 5; ++k) wn[k] = w2t[((ic+1)*5+k)*64+lane];
      }
      #pragma unroll
      for (int g = 0; g < GB; ++g) {
        float ar[16];
        const float4* rp = (const float4*)myact[g][ic];
        #pragma unroll
        for (int q = 0; q < 4; ++q) { float4 v = rp[q]; ar[4*q]=v.x; ar[4*q+1]=v.y; ar[4*q+2]=v.z; ar[4*q+3]=v.w; }
        #pragma unroll
        for (int t = 0; t < 10; ++t)
          acc[g][t] += w[0]*ar[t+1] + w[1]*ar[t+2] + w[2]*ar[t+3] + w[3]*ar[t+4] + w[4]*ar[t+5];
      }
      #pragma unroll
      for (int k = 0; k < 5; ++k) w[k] = wn[k];
    }
  }
  {
    float sc = wsr[OFF_SC2+lane], sh = wsr[OFF_SH2+lane];
    __syncthreads();
    #pragma unroll
    for (int g = 0; g < GB; ++g) {
      float* row = myact[g][lane];
      row[0]=0.f; row[1]=0.f; row[2]=0.f; row[13]=0.f; row[14]=0.f; row[15]=0.f;
      #pragma unroll
      for (int t = 0; t < 10; ++t) { float v = sc*acc[g][t] + sh; row[3+t] = v > 0.f ? v : 0.f; }
    }
    __syncthreads();
  }

  // ---- conv3: K=7, p=3 -> idx t+k ----
  #pragma unroll
  for (int g = 0; g < GB; ++g)
    #pragma unroll
    for (int t = 0; t < 10; ++t) acc[g][t] = 0.f;
  {
    float w[7], wn[7];
    #pragma unroll
    for (int k = 0; k < 7; ++k) w[k] = w3t[k*64+lane];
    for (int ic = 0; ic < 64; ++ic) {
      if (ic < 63) {
        #pragma unroll
        for (int k = 0; k < 7; ++k) wn[k] = w3t[((ic+1)*7+k)*64+lane];
      }
      #pragma unroll
      for (int g = 0; g < GB; ++g) {
        float ar[16];
        const float4* rp = (const float4*)myact[g][ic];
        #pragma unroll
        for (int q = 0; q < 4; ++q) { float4 v = rp[q]; ar[4*q]=v.x; ar[4*q+1]=v.y; ar[4*q+2]=v.z; ar[4*q+3]=v.w; }
        #pragma unroll
        for (int t = 0; t < 10; ++t)
          acc[g][t] += w[0]*ar[t+0] + w[1]*ar[t+1] + w[2]*ar[t+2] + w[3]*ar[t+3]
                     + w[4]*ar[t+4] + w[5]*ar[t+5] + w[6]*ar[t+6];
      }
      #pragma unroll
      for (int k = 0; k < 7; ++k) w[k] = wn[k];
    }
  }
  {
    float sc = wsr[OFF_SC3+lane], sh = wsr[OFF_SH3+lane];
    #pragma unroll
    for (int g = 0; g < GB; ++g) {
      float m = 0.f;
      #pragma unroll
      for (int t = 0; t < 10; ++t) { float v = sc*acc[g][t] + sh; m += (v > 0.f ? v : 0.f); }
      sfp[(size_t)(bg+g)*64 + lane] = m * 0.1f;
    }
  }
}

// ============================ RNN ============================
__global__ __launch_bounds__(256) void rnn_kernel(
    const float* __restrict__ x, const float* __restrict__ wsr,
    const float* __restrict__ A, float* __restrict__ hout)
{
  int tid = blockIdx.x * 256 + threadIdx.x;
  int b = tid >> 4;
  int j = tid & 15;

  float Arow[16];
  const float4* Ap = (const float4*)(A + j*16);
  #pragma unroll
  for (int q = 0; q < 4; ++q) { float4 v = Ap[q]; Arow[4*q]=v.x; Arow[4*q+1]=v.y; Arow[4*q+2]=v.z; Arow[4*q+3]=v.w; }
  float pb0 = wsr[OFF_PB + 0*16 + j];
  float pb1 = wsr[OFF_PB + 1*16 + j];
  float pb2 = wsr[OFF_PB + 2*16 + j];
  float pb3 = wsr[OFF_PB + 3*16 + j];
  float biasv = wsr[OFF_PBB + j];

  const float4* xb = (const float4*)(x + (size_t)b*400);
  float h = 0.f;
  float4 cur[5], nxt[5];
  #pragma unroll
  for (int q = 0; q < 5; ++q) cur[q] = xb[q];
  for (int tc = 0; tc < 100; tc += 5) {
    if (tc + 5 < 100) {
      #pragma unroll
      for (int q = 0; q < 5; ++q) nxt[q] = xb[tc+5+q];
    }
    #pragma unroll
    for (int q = 0; q < 5; ++q) {
      float4 cx = cur[q];
      float u = biasv + cx.x*pb0 + cx.y*pb1 + cx.z*pb2 + cx.w*pb3;
      #pragma unroll
      for (int i = 0; i < 16; ++i)
        u += __shfl(h, i, 16) * Arow[i];
      float e = __expf(2.f*u);
      h = 1.f - 2.f/(e + 1.f);
    }
    #pragma unroll
    for (int q = 0; q < 5; ++q) cur[q] = nxt[q];
  }
  hout[(size_t)b*16 + j] = h;
}

// ============================ tail ============================
__global__ __launch_bounds__(256) void tail_kernel(
    const float* __restrict__ wsr,
    const float* __restrict__ g1_w, const float* __restrict__ g1_b,
    const float* __restrict__ g2_w, const float* __restrict__ g2_b,
    const float* __restrict__ h1_w, const float* __restrict__ h1_b,
    const float* __restrict__ h2_w, const float* __restrict__ h2_b,
    const float* __restrict__ out_b, float* __restrict__ out)
{
  __shared__ float sG1[128*64];   // 32 KB
  __shared__ float sG2[64*64];    // 16 KB
  __shared__ float wbuf[4][128];
  __shared__ float tbuf[4][64];
  int tid = threadIdx.x;
  for (int i = tid; i < 128*64; i += 256) sG1[i] = g1_w[i];
  for (int i = tid; i < 64*64; i += 256) sG2[i] = g2_w[i];
  __syncthreads();

  int lane = tid & 63, wid = tid >> 6;
  const float* sf = wsr + OFF_SF;
  const float* hws = wsr + OFF_H;
  const float* CO = wsr + OFF_CO;
  float g1bv = g1_b[lane], g2bv = g2_b[lane], obv = out_b[lane];
  float h1bv = (lane < 32) ? h1_b[lane] : 0.f;

  int b0 = blockIdx.x * 32 + wid * 8;
  for (int it = 0; it < 8; ++it) {
    int b = b0 + it;
    float sfv = sf[(size_t)b*64 + lane];
    float lcv = obv;
    {
      float hj[16];
      const float4* hp = (const float4*)(hws + (size_t)b*16);
      #pragma unroll
      for (int q = 0; q < 4; ++q) { float4 v = hp[q]; hj[4*q]=v.x; hj[4*q+1]=v.y; hj[4*q+2]=v.z; hj[4*q+3]=v.w; }
      #pragma unroll
      for (int j = 0; j < 16; ++j) lcv += hj[j]*CO[j*64+lane];
    }
    wbuf[wid][lane] = sfv;
    wbuf[wid][64+lane] = lcv;
    __syncthreads();
    float u = g1bv;
    #pragma unroll 8
    for (int k = 0; k < 128; ++k) u += wbuf[wid][k]*sG1[k*64+lane];
    float e1 = __expf(2.f*u);
    float t1 = 1.f - 2.f/(e1 + 1.f);
    __syncthreads();
    tbuf[wid][lane] = t1;
    __syncthreads();
    float u2 = g2bv;
    #pragma unroll 8
    for (int k = 0; k < 64; ++k) u2 += tbuf[wid][k]*sG2[k*64+lane];
    float gate = 1.f/(1.f + __expf(-u2));
    float filt = sfv * gate;
    __syncthreads();
    wbuf[wid][lane] = filt;
    __syncthreads();
    float r = 0.f;
    if (lane < 32) {
      r = h1bv;
      #pragma unroll 8
      for (int k = 0; k < 64; ++k) r += wbuf[wid][k]*h1_w[k*32+lane];
      r = fmaxf(r, 0.f);
    }
    __syncthreads();
    if (lane < 32) tbuf[wid][lane] = r;
    __syncthreads();
    if (lane < 3) {
      float a = h2_b[lane];
      #pragma unroll
      for (int m = 0; m < 32; ++m) a += tbuf[wid][m]*h2_w[m*3+lane];
      out[(size_t)b*3 + lane] = a;
    }
    __syncthreads();
  }
}

// ============================ launch ============================
extern "C" void kernel_launch(void* const* d_in, const int* in_sizes, int n_in,
                              void* d_out, int out_size, void* d_ws, size_t ws_size,
                              hipStream_t stream) {
  const float* x       = (const float*)d_in[0];
  const float* conv1_w = (const float*)d_in[1];
  const float* conv1_b = (const float*)d_in[2];
  const float* conv2_w = (const float*)d_in[3];
  const float* conv2_b = (const float*)d_in[4];
  const float* conv3_w = (const float*)d_in[5];
  const float* conv3_b = (const float*)d_in[6];
  const float* bn1_g   = (const float*)d_in[7];
  const float* bn1_b   = (const float*)d_in[8];
  const float* bn2_g   = (const float*)d_in[9];
  const float* bn2_b   = (const float*)d_in[10];
  const float* bn3_g   = (const float*)d_in[11];
  const float* bn3_b   = (const float*)d_in[12];
  const float* proj_w  = (const float*)d_in[13];
  const float* proj_b  = (const float*)d_in[14];
  const float* A       = (const float*)d_in[15];
  const float* Bm      = (const float*)d_in[16];
  const float* Cm      = (const float*)d_in[17];
  const float* out_w   = (const float*)d_in[18];
  const float* out_b   = (const float*)d_in[19];
  const float* g1_w    = (const float*)d_in[20];
  const float* g1_b    = (const float*)d_in[21];
  const float* g2_w    = (const float*)d_in[22];
  const float* g2_b    = (const float*)d_in[23];
  const float* h1_w    = (const float*)d_in[24];
  const float* h1_b    = (const float*)d_in[25];
  const float* h2_w    = (const float*)d_in[26];
  const float* h2_b    = (const float*)d_in[27];
  float* ws = (float*)d_ws;
  float* out = (float*)d_out;

  prep_kernel<<<64, 256, 0, stream>>>(conv1_w, conv1_b, conv2_w, conv2_b,
      conv3_w, conv3_b, bn1_g, bn1_b, bn2_g, bn2_b, bn3_g, bn3_b,
      proj_w, proj_b, A, Bm, Cm, out_w, ws);
  conv_kernel<<<NB/(2*GB), 128, 0, stream>>>(x, ws, ws + OFF_SF);
  rnn_kernel<<<NB*16/256, 256, 0, stream>>>(x, ws, A, ws + OFF_H);
  tail_kernel<<<NB/32, 256, 0, stream>>>(ws, g1_w, g1_b, g2_w, g2_b,
      h1_w, h1_b, h2_w, h2_b, out_b, out);
}

// Round 3
// 482.489 us; speedup vs baseline: 1.1135x; 1.1135x over previous
//
#include <hip/hip_runtime.h>
#include <cstddef>

#define NB 16384
#define NGRP 8

typedef __attribute__((ext_vector_type(8))) _Float16 half8;
typedef __attribute__((ext_vector_type(4))) _Float16 half4;
typedef __attribute__((ext_vector_type(4))) float f32x4;
typedef __attribute__((ext_vector_type(16))) float f32x16;

// ---- ws float offsets ----
#define OFF_W1T 0                      // 12*64
#define OFF_SC1 768
#define OFF_SH1 832
#define OFF_SC2 896
#define OFF_SH2 960
#define OFF_SC3 1024
#define OFF_SH3 1088
#define OFF_PB  1152                   // 4*16
#define OFF_PBB 1216                   // 16
#define OFF_CO  1232                   // 16*64 -> 2256
#define OFF_W2H 2304                   // 20*2*64*8 halves = 10240 floats
#define OFF_W2L 12544                  // 10240 floats
#define OFF_W3H 22784                  // 28*2*64*8 halves = 14336 floats
#define OFF_W3L 37120                  // 14336 floats
#define OFF_SF  51456                  // NB*64
#define OFF_H   (51456 + NB*64)        // NB*16

// ============================ prep ============================
__global__ __launch_bounds__(256) void prep_kernel(
    const float* __restrict__ conv1_w, const float* __restrict__ conv1_b,
    const float* __restrict__ conv2_w, const float* __restrict__ conv2_b,
    const float* __restrict__ conv3_w, const float* __restrict__ conv3_b,
    const float* __restrict__ bn1_g, const float* __restrict__ bn1_b,
    const float* __restrict__ bn2_g, const float* __restrict__ bn2_b,
    const float* __restrict__ bn3_g, const float* __restrict__ bn3_b,
    const float* __restrict__ proj_w, const float* __restrict__ proj_b,
    const float* __restrict__ A, const float* __restrict__ Bm,
    const float* __restrict__ Cm, const float* __restrict__ out_w,
    float* __restrict__ ws)
{
  int tid = blockIdx.x * blockDim.x + threadIdx.x;
  int nt = gridDim.x * blockDim.x;
  const float s = rsqrtf(1.0f + 1e-5f);

  for (int i = tid; i < 64*12; i += nt) {       // w1t[(c*3+k)*64+o]
    int o = i & 63, rk = i >> 6;
    ws[OFF_W1T + i] = conv1_w[o*12 + rk];
  }
  for (int o = tid; o < 64; o += nt) {
    float s1 = bn1_g[o]*s, s2 = bn2_g[o]*s, s3 = bn3_g[o]*s;
    ws[OFF_SC1+o] = s1; ws[OFF_SH1+o] = s1*conv1_b[o] + bn1_b[o];
    ws[OFF_SC2+o] = s2; ws[OFF_SH2+o] = s2*conv2_b[o] + bn2_b[o];
    ws[OFF_SC3+o] = s3; ws[OFF_SH3+o] = s3*conv3_b[o] + bn3_b[o];
  }
  // conv2 A-fragments for 32x32x16, k = tap*64 + ic (tap-major), hi/lo split.
  // frag s (k-step), otile ot, lane l: o = ot*32+(l&31), ic = (s&3)*16+(l>>5)*8+j
  {
    _Float16* w2h = (_Float16*)(ws + OFF_W2H);
    _Float16* w2l = (_Float16*)(ws + OFF_W2L);
    for (int i = tid; i < 20*2*64; i += nt) {
      int lane = i & 63, ot = (i >> 6) & 1, sk = i >> 7;
      int tap = sk >> 2, ic0 = (sk & 3)*16 + (lane >> 5)*8;
      int o = ot*32 + (lane & 31);
      #pragma unroll
      for (int j = 0; j < 8; ++j) {
        float w = conv2_w[o*320 + (ic0 + j)*5 + tap];
        _Float16 hi = (_Float16)w;
        w2h[(size_t)i*8 + j] = hi;
        w2l[(size_t)i*8 + j] = (_Float16)(w - (float)hi);
      }
    }
  }
  {
    _Float16* w3h = (_Float16*)(ws + OFF_W3H);
    _Float16* w3l = (_Float16*)(ws + OFF_W3L);
    for (int i = tid; i < 28*2*64; i += nt) {
      int lane = i & 63, ot = (i >> 6) & 1, sk = i >> 7;
      int tap = sk >> 2, ic0 = (sk & 3)*16 + (lane >> 5)*8;
      int o = ot*32 + (lane & 31);
      #pragma unroll
      for (int j = 0; j < 8; ++j) {
        float w = conv3_w[o*448 + (ic0 + j)*7 + tap];
        _Float16 hi = (_Float16)w;
        w3h[(size_t)i*8 + j] = hi;
        w3l[(size_t)i*8 + j] = (_Float16)(w - (float)hi);
      }
    }
  }
  // PB[c][j] = sum_m proj_w[c][m]*Bm[m][j]
  for (int i = tid; i < 64; i += nt) {
    int c = i >> 4, j = i & 15;
    float acc = 0.f;
    for (int m = 0; m < 64; ++m) acc += proj_w[c*64+m]*Bm[m*16+j];
    ws[OFF_PB + i] = acc;
  }
  for (int j = tid; j < 16; j += nt) {
    float acc = 0.f;
    for (int m = 0; m < 64; ++m) acc += proj_b[m]*Bm[m*16+j];
    ws[OFF_PBB + j] = acc;
  }
  // CO[j][o] = sum_m Cm[j][m]*out_w[m][o]
  for (int i = tid; i < 16*64; i += nt) {
    int j = i >> 6, o = i & 63;
    float acc = 0.f;
    for (int m = 0; m < 64; ++m) acc += Cm[j*64+m]*out_w[m*64+o];
    ws[OFF_CO + i] = acc;
  }
}

// ============================ conv stack (MFMA f16, 3-term split) ============================
// act tiles: [local batch 0..3][slot 0..15][ic 0..63 (+8 pad)], slot = t_in + 3.
// conv2 slot = n + tap + 1 (tap 0..4); conv3 slot = n + tap (tap 0..6).
// Wave wid: otile ot = wid&1 (o's [ot*32,ot*32+32)), pair p = wid>>1 (batches 2p,2p+1).
// MFMA 32x32x16: B cols = batch_in_pair*16 + n; lane's col = lane&31.
// C/D: col = lane&31, row = (reg&3) + 8*(reg>>2) + 4*(lane>>5).
__global__ __launch_bounds__(256, 2) void conv_kernel(
    const float* __restrict__ x, const float* __restrict__ wsr,
    float* __restrict__ sfp)
{
  __shared__ __align__(16) _Float16 act1h[4][16][72];
  __shared__ __align__(16) _Float16 act1l[4][16][72];
  __shared__ __align__(16) _Float16 act2h[4][16][72];
  __shared__ __align__(16) _Float16 act2l[4][16][72];
  __shared__ float xs[4][4][12];

  const int tid = threadIdx.x;
  const int lane = tid & 63;
  const int wid = tid >> 6;
  const int ot = wid & 1;
  const int p = wid >> 1;
  const int n = lane & 15;
  const int nc = (n < 10) ? n : 9;       // clamp; junk cols discarded in epilogue
  const int lb = 2*p + ((lane >> 4) & 1); // local batch this lane's column belongs to
  const int kh = (lane >> 5) * 8;         // k-half offset within a 16-k step
  const int rq = 4*(lane >> 5) + ot*32;   // row-base component

  { // zero-init LDS pads
    unsigned* p1 = (unsigned*)&act1h[0][0][0];
    unsigned* p2 = (unsigned*)&act1l[0][0][0];
    unsigned* p3 = (unsigned*)&act2h[0][0][0];
    unsigned* p4 = (unsigned*)&act2l[0][0][0];
    for (int i = tid; i < 4*16*72/2; i += 256) { p1[i]=0u; p2[i]=0u; p3[i]=0u; p4[i]=0u; }
    float* px = &xs[0][0][0];
    for (int i = tid; i < 4*4*12; i += 256) px[i] = 0.f;
  }

  // weight fragments -> registers (96 half8 = 192 VGPRs)
  half8 w2h[20], w2l[20], w3h[28], w3l[28];
  #pragma unroll
  for (int sk = 0; sk < 20; ++sk) {
    w2h[sk] = *(const half8*)(wsr + OFF_W2H + (size_t)((sk*2 + ot)*64 + lane)*4);
    w2l[sk] = *(const half8*)(wsr + OFF_W2L + (size_t)((sk*2 + ot)*64 + lane)*4);
  }
  #pragma unroll
  for (int sk = 0; sk < 28; ++sk) {
    w3h[sk] = *(const half8*)(wsr + OFF_W3H + (size_t)((sk*2 + ot)*64 + lane)*4);
    w3l[sk] = *(const half8*)(wsr + OFF_W3L + (size_t)((sk*2 + ot)*64 + lane)*4);
  }

  __syncthreads();

  for (int it = 0; it < NGRP; ++it) {
    const int bg = (blockIdx.x * NGRP + it) * 4;

    // ---- stage x window: wave wid stages batch bg+wid ----
    if (lane < 40)
      xs[wid][lane & 3][1 + (lane >> 2)] = x[(size_t)(bg + wid)*400 + 360 + lane];
    __syncthreads();   // B0: also fences next-iter act1 writes vs prev conv2 reads

    // ---- conv1 (fp32 VALU, K=12): lane = out channel, batch = wid ----
    {
      float a1[10];
      #pragma unroll
      for (int t = 0; t < 10; ++t) a1[t] = 0.f;
      #pragma unroll
      for (int c = 0; c < 4; ++c)
        #pragma unroll
        for (int k = 0; k < 3; ++k) {
          const float wv = wsr[OFF_W1T + (c*3 + k)*64 + lane];
          #pragma unroll
          for (int t = 0; t < 10; ++t) a1[t] += wv * xs[wid][c][t + k];
        }
      const float sc1 = wsr[OFF_SC1 + lane], sh1 = wsr[OFF_SH1 + lane];
      #pragma unroll
      for (int t = 0; t < 10; ++t) {
        float v = sc1 * a1[t] + sh1;
        v = v > 0.f ? v : 0.f;
        _Float16 hi = (_Float16)v;
        act1h[wid][3 + t][lane] = hi;
        act1l[wid][3 + t][lane] = (_Float16)(v - (float)hi);
      }
    }
    __syncthreads();   // B1

    // ---- conv2: 20 k-steps x 3 split terms ----
    {
      f32x16 acc;
      #pragma unroll
      for (int r = 0; r < 16; ++r) acc[r] = 0.f;
      #pragma unroll
      for (int sk = 0; sk < 20; ++sk) {
        const int tap = sk >> 2, icb = (sk & 3) * 16;
        const half8 bh = *(const half8*)(&act1h[lb][nc + tap + 1][icb + kh]);
        const half8 bl = *(const half8*)(&act1l[lb][nc + tap + 1][icb + kh]);
        acc = __builtin_amdgcn_mfma_f32_32x32x16_f16(w2h[sk], bh, acc, 0, 0, 0);
        acc = __builtin_amdgcn_mfma_f32_32x32x16_f16(w2h[sk], bl, acc, 0, 0, 0);
        acc = __builtin_amdgcn_mfma_f32_32x32x16_f16(w2l[sk], bh, acc, 0, 0, 0);
      }
      if (n < 10) {
        #pragma unroll
        for (int q = 0; q < 4; ++q) {
          const int rowb = 8*q + rq;
          const f32x4 sc = *(const f32x4*)(wsr + OFF_SC2 + rowb);
          const f32x4 sh = *(const f32x4*)(wsr + OFF_SH2 + rowb);
          half4 h4, l4;
          #pragma unroll
          for (int r = 0; r < 4; ++r) {
            float v = sc[r]*acc[4*q + r] + sh[r];
            v = v > 0.f ? v : 0.f;
            _Float16 hi = (_Float16)v;
            h4[r] = hi;
            l4[r] = (_Float16)(v - (float)hi);
          }
          *(half4*)(&act2h[lb][n + 3][rowb]) = h4;
          *(half4*)(&act2l[lb][n + 3][rowb]) = l4;
        }
      }
    }
    __syncthreads();   // B2

    // ---- conv3: 28 k-steps x 3 split terms + mean + store ----
    {
      f32x16 acc;
      #pragma unroll
      for (int r = 0; r < 16; ++r) acc[r] = 0.f;
      #pragma unroll
      for (int sk = 0; sk < 28; ++sk) {
        const int tap = sk >> 2, icb = (sk & 3) * 16;
        const half8 bh = *(const half8*)(&act2h[lb][nc + tap][icb + kh]);
        const half8 bl = *(const half8*)(&act2l[lb][nc + tap][icb + kh]);
        acc = __builtin_amdgcn_mfma_f32_32x32x16_f16(w3h[sk], bh, acc, 0, 0, 0);
        acc = __builtin_amdgcn_mfma_f32_32x32x16_f16(w3h[sk], bl, acc, 0, 0, 0);
        acc = __builtin_amdgcn_mfma_f32_32x32x16_f16(w3l[sk], bh, acc, 0, 0, 0);
      }
      #pragma unroll
      for (int q = 0; q < 4; ++q) {
        const int rowb = 8*q + rq;
        const f32x4 sc = *(const f32x4*)(wsr + OFF_SC3 + rowb);
        const f32x4 sh = *(const f32x4*)(wsr + OFF_SH3 + rowb);
        f32x4 v;
        #pragma unroll
        for (int r = 0; r < 4; ++r) {
          float t = sc[r]*acc[4*q + r] + sh[r];
          t = t > 0.f ? t : 0.f;
          v[r] = (n < 10) ? t : 0.f;
        }
        #pragma unroll
        for (int r = 0; r < 4; ++r) {
          v[r] += __shfl_xor(v[r], 1, 16);
          v[r] += __shfl_xor(v[r], 2, 16);
          v[r] += __shfl_xor(v[r], 4, 16);
          v[r] += __shfl_xor(v[r], 8, 16);
        }
        if (n == 0)
          *(f32x4*)(sfp + (size_t)(bg + lb)*64 + rowb) = v * 0.1f;
      }
    }
    // next-iter B0 fences act1/act2 rewrites
  }
}

// ============================ RNN ============================
__global__ __launch_bounds__(256) void rnn_kernel(
    const float* __restrict__ x, const float* __restrict__ wsr,
    const float* __restrict__ A, float* __restrict__ hout)
{
  int tid = blockIdx.x * 256 + threadIdx.x;
  int b = tid >> 4;
  int j = tid & 15;

  float Arow[16];
  const float4* Ap = (const float4*)(A + j*16);
  #pragma unroll
  for (int q = 0; q < 4; ++q) { float4 v = Ap[q]; Arow[4*q]=v.x; Arow[4*q+1]=v.y; Arow[4*q+2]=v.z; Arow[4*q+3]=v.w; }
  float pb0 = wsr[OFF_PB + 0*16 + j];
  float pb1 = wsr[OFF_PB + 1*16 + j];
  float pb2 = wsr[OFF_PB + 2*16 + j];
  float pb3 = wsr[OFF_PB + 3*16 + j];
  float biasv = wsr[OFF_PBB + j];

  const float4* xb = (const float4*)(x + (size_t)b*400);
  float h = 0.f;
  float4 cur[5], nxt[5];
  #pragma unroll
  for (int q = 0; q < 5; ++q) cur[q] = xb[q];
  for (int tc = 0; tc < 100; tc += 5) {
    if (tc + 5 < 100) {
      #pragma unroll
      for (int q = 0; q < 5; ++q) nxt[q] = xb[tc+5+q];
    }
    #pragma unroll
    for (int q = 0; q < 5; ++q) {
      float4 cx = cur[q];
      float u = biasv + cx.x*pb0 + cx.y*pb1 + cx.z*pb2 + cx.w*pb3;
      #pragma unroll
      for (int i = 0; i < 16; ++i)
        u += __shfl(h, i, 16) * Arow[i];
      float e = __expf(2.f*u);
      h = 1.f - 2.f/(e + 1.f);
    }
    #pragma unroll
    for (int q = 0; q < 5; ++q) cur[q] = nxt[q];
  }
  hout[(size_t)b*16 + j] = h;
}

// ============================ tail ============================
__global__ __launch_bounds__(256) void tail_kernel(
    const float* __restrict__ wsr,
    const float* __restrict__ g1_w, const float* __restrict__ g1_b,
    const float* __restrict__ g2_w, const float* __restrict__ g2_b,
    const float* __restrict__ h1_w, const float* __restrict__ h1_b,
    const float* __restrict__ h2_w, const float* __restrict__ h2_b,
    const float* __restrict__ out_b, float* __restrict__ out)
{
  __shared__ float sG1[128*64];   // 32 KB
  __shared__ float sG2[64*64];    // 16 KB
  __shared__ float wbuf[4][128];
  __shared__ float tbuf[4][64];
  int tid = threadIdx.x;
  for (int i = tid; i < 128*64; i += 256) sG1[i] = g1_w[i];
  for (int i = tid; i < 64*64; i += 256) sG2[i] = g2_w[i];
  __syncthreads();

  int lane = tid & 63, wid = tid >> 6;
  const float* sf = wsr + OFF_SF;
  const float* hws = wsr + OFF_H;
  const float* CO = wsr + OFF_CO;
  float g1bv = g1_b[lane], g2bv = g2_b[lane], obv = out_b[lane];
  float h1bv = (lane < 32) ? h1_b[lane] : 0.f;

  int b0 = blockIdx.x * 32 + wid * 8;
  for (int it = 0; it < 8; ++it) {
    int b = b0 + it;
    float sfv = sf[(size_t)b*64 + lane];
    float lcv = obv;
    {
      float hj[16];
      const float4* hp = (const float4*)(hws + (size_t)b*16);
      #pragma unroll
      for (int q = 0; q < 4; ++q) { float4 v = hp[q]; hj[4*q]=v.x; hj[4*q+1]=v.y; hj[4*q+2]=v.z; hj[4*q+3]=v.w; }
      #pragma unroll
      for (int j = 0; j < 16; ++j) lcv += hj[j]*CO[j*64+lane];
    }
    wbuf[wid][lane] = sfv;
    wbuf[wid][64+lane] = lcv;
    __syncthreads();
    float u = g1bv;
    #pragma unroll 8
    for (int k = 0; k < 128; ++k) u += wbuf[wid][k]*sG1[k*64+lane];
    float e1 = __expf(2.f*u);
    float t1 = 1.f - 2.f/(e1 + 1.f);
    __syncthreads();
    tbuf[wid][lane] = t1;
    __syncthreads();
    float u2 = g2bv;
    #pragma unroll 8
    for (int k = 0; k < 64; ++k) u2 += tbuf[wid][k]*sG2[k*64+lane];
    float gate = 1.f/(1.f + __expf(-u2));
    float filt = sfv * gate;
    __syncthreads();
    wbuf[wid][lane] = filt;
    __syncthreads();
    float r = 0.f;
    if (lane < 32) {
      r = h1bv;
      #pragma unroll 8
      for (int k = 0; k < 64; ++k) r += wbuf[wid][k]*h1_w[k*32+lane];
      r = fmaxf(r, 0.f);
    }
    __syncthreads();
    if (lane < 32) tbuf[wid][lane] = r;
    __syncthreads();
    if (lane < 3) {
      float a = h2_b[lane];
      #pragma unroll
      for (int m = 0; m < 32; ++m) a += tbuf[wid][m]*h2_w[m*3+lane];
      out[(size_t)b*3 + lane] = a;
    }
    __syncthreads();
  }
}

// ============================ launch ============================
extern "C" void kernel_launch(void* const* d_in, const int* in_sizes, int n_in,
                              void* d_out, int out_size, void* d_ws, size_t ws_size,
                              hipStream_t stream) {
  const float* x       = (const float*)d_in[0];
  const float* conv1_w = (const float*)d_in[1];
  const float* conv1_b = (const float*)d_in[2];
  const float* conv2_w = (const float*)d_in[3];
  const float* conv2_b = (const float*)d_in[4];
  const float* conv3_w = (const float*)d_in[5];
  const float* conv3_b = (const float*)d_in[6];
  const float* bn1_g   = (const float*)d_in[7];
  const float* bn1_b   = (const float*)d_in[8];
  const float* bn2_g   = (const float*)d_in[9];
  const float* bn2_b   = (const float*)d_in[10];
  const float* bn3_g   = (const float*)d_in[11];
  const float* bn3_b   = (const float*)d_in[12];
  const float* proj_w  = (const float*)d_in[13];
  const float* proj_b  = (const float*)d_in[14];
  const float* A       = (const float*)d_in[15];
  const float* Bm      = (const float*)d_in[16];
  const float* Cm      = (const float*)d_in[17];
  const float* out_w   = (const float*)d_in[18];
  const float* out_b   = (const float*)d_in[19];
  const float* g1_w    = (const float*)d_in[20];
  const float* g1_b    = (const float*)d_in[21];
  const float* g2_w    = (const float*)d_in[22];
  const float* g2_b    = (const float*)d_in[23];
  const float* h1_w    = (const float*)d_in[24];
  const float* h1_b    = (const float*)d_in[25];
  const float* h2_w    = (const float*)d_in[26];
  const float* h2_b    = (const float*)d_in[27];
  float* ws = (float*)d_ws;
  float* out = (float*)d_out;

  prep_kernel<<<64, 256, 0, stream>>>(conv1_w, conv1_b, conv2_w, conv2_b,
      conv3_w, conv3_b, bn1_g, bn1_b, bn2_g, bn2_b, bn3_g, bn3_b,
      proj_w, proj_b, A, Bm, Cm, out_w, ws);
  conv_kernel<<<NB/(4*NGRP), 256, 0, stream>>>(x, ws, ws + OFF_SF);
  rnn_kernel<<<NB*16/256, 256, 0, stream>>>(x, ws, A, ws + OFF_H);
  tail_kernel<<<NB/32, 256, 0, stream>>>(ws, g1_w, g1_b, g2_w, g2_b,
      h1_w, h1_b, h2_w, h2_b, out_b, out);
}